// Round 4
// baseline (109.338 us; speedup 1.0000x reference)
//
#include <hip/hip_runtime.h>

// Bilateral slicing (HDRNet).
// grid  : [B=8][C=12][D=8][Hg=16][Wg=16] fp32  (logical [B,Hg,Wg,D,C] after ref transpose)
// guide : [B=8][1][H=1024][W=1024] fp32 in [0,1)
// out   : [B=8][C=12][H=1024][W=1024] fp32

#define BB 8
#define CC 12
#define DD 8
#define HG 16
#define WG 16
#define HH 1024
#define WW 1024
#define RROWS 8
#define NBLK (BB * (HH / RROWS))   // 1024 blocks = 4 per CU, all resident

__global__ __launch_bounds__(256) void slice_kernel(
    const float* __restrict__ grid,
    const float* __restrict__ guide,
    float* __restrict__ out)
{
    // raw y-planes (yb, yb+1) and double-buffered per-row y-interp slices
    // layout [c][xg][z], z contiguous (ds_read2-friendly, data-dep z per lane)
    __shared__ float P[2][CC * WG * DD];   // 12 KB
    __shared__ float S[2][CC * WG * DD];   // 12 KB

    // XCD-contiguous swizzle: XCD k (= blockIdx.x & 7) owns batch b = k and
    // sweeps row-groups in dispatch order -> 12 long sequential write streams
    // per XCD instead of thousands of scattered 4 KB bursts.
    const int n   = blockIdx.x;
    const int n2  = (n & 7) * (NBLK / 8) + (n >> 3);   // bijective, NBLK % 8 == 0
    const int b   = n2 >> 7;                           // n2 / 128
    const int rg  = n2 & 127;
    const int y0  = rg * RROWS;
    const int tid = threadIdx.x;

    // ---- group-uniform y cell: rows y0..y0+7 share floor(ty) (changes at y%64==32) ----
    const float ty0 = ((float)y0 + 0.5f) * (1.0f / 64.0f) - 0.5f;
    const int   yb  = (int)fminf(fmaxf(floorf(ty0), 0.0f), (float)(HG - 2));

    // ---- stage both raw y-planes into LDS (transposed to [c][xg][z]) ----
    const float* gb = grid + (size_t)b * (CC * DD * HG * WG);
    #pragma unroll
    for (int k = 0; k < 12; ++k) {
        const int i  = tid + k * 256;        // 0..3071
        const int p  = (i >= CC * WG * DD) ? 1 : 0;
        const int j  = i - p * (CC * WG * DD);
        const int c  = j >> 7;               // /128
        const int r  = j & 127;
        const int z  = r >> 4;               // /16
        const int xg = r & 15;
        P[p][c * (WG * DD) + xg * DD + z] =
            gb[(size_t)(c * DD + z) * (HG * WG) + (yb + p) * WG + xg];
    }
    __syncthreads();

    const int x0 = tid * 4;
    const float* guider = guide + ((size_t)b * HH + y0) * WW + x0;
    float*       outr   = out + ((size_t)(b * CC) * HH + y0) * WW + x0;

    #pragma unroll
    for (int rrow = 0; rrow < RROWS; ++rrow) {
        const int y = y0 + rrow;

        // per-row y weights (yb is group-uniform)
        const float ty  = ((float)y + 0.5f) * (1.0f / 64.0f) - 0.5f;
        const float wy1 = fminf(fmaxf(ty - (float)yb, 0.0f), 1.0f);
        const float wy0 = 1.0f - wy1;

        // build this row's y-interpolated slice (double-buffered; the barrier
        // below also protects buffer reuse two rows later)
        float* Sr = S[rrow & 1];
        #pragma unroll
        for (int k = 0; k < 6; ++k) {
            const int i = tid + k * 256;
            Sr[i] = wy0 * P[0][i] + wy1 * P[1][i];
        }
        __syncthreads();

        // ---- consume: 4 px per thread, float4 I/O ----
        const float4 g4 = *(const float4*)(guider + (size_t)rrow * WW);
        const float gvals[4] = {g4.x, g4.y, g4.z, g4.w};

        float w00[4], w01[4], w10[4], w11[4];
        int a0[4];
        #pragma unroll
        for (int p = 0; p < 4; ++p) {
            const float gz  = gvals[p] * 8.0f;
            const float tz  = gz - 0.5f;
            const int   zb  = (int)fminf(fmaxf(floorf(tz), 0.0f), (float)(DD - 2));
            const float wz1 = fminf(fmaxf(tz - (float)zb, 0.0f), 1.0f);
            const float wz0 = 1.0f - wz1;

            const float gx  = ((float)(x0 + p) + 0.5f) * (1.0f / 64.0f);
            const float tx  = gx - 0.5f;
            const int   xb  = (int)fminf(fmaxf(floorf(tx), 0.0f), (float)(WG - 2));
            const float wx1 = fminf(fmaxf(tx - (float)xb, 0.0f), 1.0f);
            const float wx0 = 1.0f - wx1;

            w00[p] = wx0 * wz0;
            w01[p] = wx0 * wz1;
            w10[p] = wx1 * wz0;
            w11[p] = wx1 * wz1;
            a0[p]  = xb * DD + zb;
        }

        #pragma unroll
        for (int c = 0; c < CC; ++c) {
            const float* base = Sr + c * (WG * DD);
            float rr[4];
            #pragma unroll
            for (int p = 0; p < 4; ++p) {
                const float va0 = base[a0[p]];
                const float va1 = base[a0[p] + 1];
                const float vb0 = base[a0[p] + DD];
                const float vb1 = base[a0[p] + DD + 1];
                rr[p] = w00[p] * va0 + w01[p] * va1 + w10[p] * vb0 + w11[p] * vb1;
            }
            *(float4*)(outr + (size_t)c * (HH * WW) + (size_t)rrow * WW) =
                make_float4(rr[0], rr[1], rr[2], rr[3]);
        }
    }
}

extern "C" void kernel_launch(void* const* d_in, const int* in_sizes, int n_in,
                              void* d_out, int out_size, void* d_ws, size_t ws_size,
                              hipStream_t stream) {
    const float* grid  = (const float*)d_in[0];  // 8*12*8*16*16
    const float* guide = (const float*)d_in[1];  // 8*1*1024*1024
    float* out = (float*)d_out;                  // 8*12*1024*1024

    slice_kernel<<<dim3(NBLK), dim3(256), 0, stream>>>(grid, guide, out);
}

// Round 5
// 85.681 us; speedup vs baseline: 1.2761x; 1.2761x over previous
//
#include <hip/hip_runtime.h>

// Bilateral slicing (HDRNet).
// grid  : [B=8][C=12][D=8][Hg=16][Wg=16] fp32  (logical [B,Hg,Wg,D,C] after ref transpose)
// guide : [B=8][1][H=1024][W=1024] fp32 in [0,1)
// out   : [B=8][C=12][H=1024][W=1024] fp32

#define BB 8
#define CC 12
#define DD 8
#define HG 16
#define WG 16
#define HH 1024
#define WW 1024
#define ZP 9                      // padded z-stride (bank-conflict-free staging writes)
#define CSTRIDE (WG * ZP)         // 144 words per channel

__global__ __launch_bounds__(256) void slice_kernel(
    const float* __restrict__ grid,
    const float* __restrict__ guide,
    float* __restrict__ out)
{
    // y-pre-interpolated grid slice for this row: [c][xg][z], z padded to 9
    __shared__ float S[CC * CSTRIDE];   // 1728 floats = 6.9 KB

    const int y   = blockIdx.x;   // 0..1023
    const int b   = blockIdx.y;   // 0..7
    const int tid = threadIdx.x;  // 0..255

    // ---- y interpolation (block-uniform), clamped-base form ----
    const float gy  = ((float)y + 0.5f) * (1.0f / 64.0f);
    const float ty  = gy - 0.5f;
    const int   yb  = (int)fminf(fmaxf(floorf(ty), 0.0f), (float)(HG - 2));
    const float wy1 = fminf(fmaxf(ty - (float)yb, 0.0f), 1.0f);
    const float wy0 = 1.0f - wy1;

    // ---- coalesced grid staging ----
    // Rows yb and yb+1 of each (c,z) plane are 32 contiguous floats at
    // gb + (c*8+z)*256 + yb*16. 96 chunks x 8 lanes x float4 = 768 loads,
    // 3 per thread. Lane pairs (tid^4) hold the two y-planes of the same
    // (c,z,xg0..xg0+3) quad -> y-interp in-register via shfl_xor.
    const float* gb = grid + (size_t)b * (CC * DD * HG * WG);
    #pragma unroll
    for (int k = 0; k < 3; ++k) {
        const int idx   = tid + k * 256;      // 0..767
        const int chunk = idx >> 3;           // 0..95
        const int lane8 = idx & 7;
        const int c = chunk >> 3;
        const int z = chunk & 7;
        const float4 v = *(const float4*)(gb + (size_t)(c * DD + z) * (HG * WG)
                                          + yb * WG + lane8 * 4);
        const float4 o = make_float4(__shfl_xor(v.x, 4),
                                     __shfl_xor(v.y, 4),
                                     __shfl_xor(v.z, 4),
                                     __shfl_xor(v.w, 4));
        if (lane8 < 4) {   // this lane holds row yb, partner holds yb+1
            const int xg0 = lane8 * 4;
            float* dst = &S[c * CSTRIDE + xg0 * ZP + z];
            dst[0 * ZP] = wy0 * v.x + wy1 * o.x;
            dst[1 * ZP] = wy0 * v.y + wy1 * o.y;
            dst[2 * ZP] = wy0 * v.z + wy1 * o.z;
            dst[3 * ZP] = wy0 * v.w + wy1 * o.w;
        }
    }
    __syncthreads();

    // ---- per-thread: 4 consecutive pixels, float4 I/O ----
    const int x0 = tid * 4;
    const float4 g4 = *(const float4*)(guide + ((size_t)b * HH + y) * WW + x0);
    const float gvals[4] = {g4.x, g4.y, g4.z, g4.w};

    float w00[4], w01[4], w10[4], w11[4];
    int a0[4];
    #pragma unroll
    for (int p = 0; p < 4; ++p) {
        // z interpolation, clamped-base form
        const float gz  = gvals[p] * 8.0f;
        const float tz  = gz - 0.5f;
        const int   zb  = (int)fminf(fmaxf(floorf(tz), 0.0f), (float)(DD - 2));
        const float wz1 = fminf(fmaxf(tz - (float)zb, 0.0f), 1.0f);
        const float wz0 = 1.0f - wz1;

        // x interpolation, clamped-base form
        const float gx  = ((float)(x0 + p) + 0.5f) * (1.0f / 64.0f);
        const float tx  = gx - 0.5f;
        const int   xb  = (int)fminf(fmaxf(floorf(tx), 0.0f), (float)(WG - 2));
        const float wx1 = fminf(fmaxf(tx - (float)xb, 0.0f), 1.0f);
        const float wx0 = 1.0f - wx1;

        w00[p] = wx0 * wz0;
        w01[p] = wx0 * wz1;
        w10[p] = wx1 * wz0;
        w11[p] = wx1 * wz1;
        a0[p]  = xb * ZP + zb;
    }

    float* outp = out + ((size_t)(b * CC) * HH + y) * WW + x0;

    #pragma unroll
    for (int c = 0; c < CC; ++c) {
        const float* base = S + c * CSTRIDE;
        float r[4];
        #pragma unroll
        for (int p = 0; p < 4; ++p) {
            const float va0 = base[a0[p]];          // (xb,   zb)
            const float va1 = base[a0[p] + 1];      // (xb,   zb+1)
            const float vb0 = base[a0[p] + ZP];     // (xb+1, zb)
            const float vb1 = base[a0[p] + ZP + 1]; // (xb+1, zb+1)
            r[p] = w00[p] * va0 + w01[p] * va1 + w10[p] * vb0 + w11[p] * vb1;
        }
        *(float4*)(outp + (size_t)c * (HH * WW)) = make_float4(r[0], r[1], r[2], r[3]);
    }
}

extern "C" void kernel_launch(void* const* d_in, const int* in_sizes, int n_in,
                              void* d_out, int out_size, void* d_ws, size_t ws_size,
                              hipStream_t stream) {
    const float* grid  = (const float*)d_in[0];  // 8*12*8*16*16
    const float* guide = (const float*)d_in[1];  // 8*1*1024*1024
    float* out = (float*)d_out;                  // 8*12*1024*1024

    slice_kernel<<<dim3(HH, BB), dim3(256), 0, stream>>>(grid, guide, out);
}